// Round 11
// baseline (87.693 us; speedup 1.0000x reference)
//
#include <hip/hip_runtime.h>
#include <cstdint>

#define BB 256
#define NN 128
#define DD 512
#define HH 512

typedef __attribute__((ext_vector_type(8))) short bf16x8;
typedef __attribute__((ext_vector_type(16))) float f32x16;
typedef unsigned short u16;

static __device__ __forceinline__ u16 f2bf(float f) {
    union { float f; uint32_t u; } v; v.f = f;
    uint32_t u = v.u;
    return (u16)((u + 0x7FFFu + ((u >> 16) & 1u)) >> 16);
}

static __device__ __forceinline__ void gload16(const u16* g, u16* l) {
    __builtin_amdgcn_global_load_lds((const __attribute__((address_space(1))) void*)g,
                                     (__attribute__((address_space(3))) void*)l, 16, 0, 0);
}

// ---------------- W fp32 -> bf16 (once) ----------------
__global__ __launch_bounds__(256) void wconv_kernel(const float* __restrict__ W, u16* __restrict__ Wb) {
    int idx = (blockIdx.x * 256 + threadIdx.x) * 4;
    float4 v = *(const float4*)(W + idx);
    ushort4 o;
    o.x = f2bf(v.x); o.y = f2bf(v.y); o.z = f2bf(v.z); o.w = f2bf(v.w);
    *(ushort4*)(Wb + idx) = o;
}

// ================ FUSED: out = sigmoid(LN( ((I+A_norm)X) W^T + b )) ================
// 1 block per batch (256 blocks), 512 thr = 8 waves (wm = w>>2, wn = w&3).
// Phase 3/4 run as TWO row-half passes so the live accumulator is 64 regs
// (acc2[2][2]) not 128 — keeps peak register demand under the 128-VGPR
// allocation and eliminates the R9/R10 scratch spills (~100 MB/dispatch).
__global__ __launch_bounds__(512, 1) void fused_kernel(const float* __restrict__ X, const float* __restrict__ A,
                                                       const u16* __restrict__ Wb, const float* __restrict__ bias,
                                                       const float* __restrict__ lnw, const float* __restrict__ lnb,
                                                       float* __restrict__ out) {
    __shared__ __align__(16) char smem[163840];
    u16* Ms = (u16*)smem;                 // [128 i][128 m], chunk c' = c ^ (i&15)
    u16* Xt = (u16*)(smem + 32768);       // [512 d][128 m], chunk c' = c ^ ((d>>2)&7)
    float* Pss = (float*)smem;            // epilogue overlay: [4 wn][64 row][2]
    float* musig = (float*)(smem + 4096); // [64 row][2]

    const int t = threadIdx.x;
    const int lane = t & 63, w = t >> 6, l31 = lane & 31, lh = lane >> 5;
    const int batch = blockIdx.x;
    const int wm = w >> 2, wn = w & 3;

    // ---- Phase 1a: M = A_norm + I ----
    {
        const int row = t >> 2, seg = t & 3;
        const float* Ag = A + (size_t)batch * NN * NN + row * NN + seg * 32;
        float4 a[8];
        #pragma unroll
        for (int j = 0; j < 8; ++j) a[j] = *(const float4*)(Ag + j * 4);
        float s = 0.f;
        #pragma unroll
        for (int j = 0; j < 8; ++j) s += a[j].x + a[j].y + a[j].z + a[j].w;
        s += __shfl_xor(s, 1);
        s += __shfl_xor(s, 2);
        const float inv = 1.0f / (s + 1e-6f);
        #pragma unroll
        for (int c2 = 0; c2 < 4; ++c2) {
            u16 tmp[8];
            const float* pe = (const float*)&a[c2 * 2];
            #pragma unroll
            for (int e = 0; e < 8; ++e) {
                int m = seg * 32 + c2 * 8 + e;
                tmp[e] = f2bf(pe[e] * inv + (m == row ? 1.0f : 0.0f));
            }
            int c = seg * 4 + c2;
            *(uint4*)(Ms + row * 128 + ((c ^ (row & 15)) << 3)) = *(const uint4*)tmp;
        }
    }

    // ---- Phase 1b: Xt[d][m] = X[m][d] bf16 swizzled ----
    {
        const float* Xg = X + (size_t)batch * NN * DD;
        #pragma unroll
        for (int it = 0; it < 32; ++it) {
            int q = it * 512 + t;
            int m = q >> 7, c4 = q & 127;
            float4 v = *(const float4*)(Xg + (size_t)m * DD + c4 * 4);
            float fv[4] = {v.x, v.y, v.z, v.w};
            #pragma unroll
            for (int j = 0; j < 4; ++j) {
                int d = c4 * 4 + j;
                Xt[d * 128 + (((m >> 3) ^ ((d >> 2) & 7)) << 3) + (m & 7)] = f2bf(fv[j]);
            }
        }
    }
    __syncthreads();

    // ---- Phase 2: GEMM1 (M @ X) per d-half; overlay Xagg bf16 onto dead Xt half ----
    // Xagg half dh at byte 32768 + dh*65536: [128 i][256 dl], row stride 512B,
    // chunk cloc' = cloc ^ (i&7)
    #pragma unroll
    for (int dh = 0; dh < 2; ++dh) {
        f32x16 acc1[2][2];
        #pragma unroll
        for (int fi = 0; fi < 2; ++fi)
            #pragma unroll
            for (int fd = 0; fd < 2; ++fd)
                #pragma unroll
                for (int r = 0; r < 16; ++r)
                    acc1[fi][fd][r] = 0.f;

        #pragma unroll
        for (int ksl = 0; ksl < 8; ++ksl) {
            const int kc = ksl * 2 + lh;
            bf16x8 af[2], bx[2];
            #pragma unroll
            for (int fi = 0; fi < 2; ++fi) {
                int i = wm * 64 + fi * 32 + l31;
                af[fi] = *(const bf16x8*)(Ms + i * 128 + ((kc ^ (i & 15)) << 3));
            }
            #pragma unroll
            for (int fd = 0; fd < 2; ++fd) {
                int d = dh * 256 + wn * 64 + fd * 32 + l31;
                bx[fd] = *(const bf16x8*)(Xt + d * 128 + ((kc ^ ((d >> 2) & 7)) << 3));
            }
            #pragma unroll
            for (int fi = 0; fi < 2; ++fi)
                #pragma unroll
                for (int fd = 0; fd < 2; ++fd)
                    acc1[fi][fd] = __builtin_amdgcn_mfma_f32_32x32x16_bf16(af[fi], bx[fd], acc1[fi][fd], 0, 0, 0);
        }
        __syncthreads();   // all waves done reading Xt half dh

        char* Xa = smem + 32768 + dh * 65536;
        #pragma unroll
        for (int fi = 0; fi < 2; ++fi)
            #pragma unroll
            for (int r = 0; r < 16; ++r) {
                int i = wm * 64 + fi * 32 + (r & 3) + 8 * (r >> 2) + 4 * lh;
                #pragma unroll
                for (int fd = 0; fd < 2; ++fd) {
                    int dl = wn * 64 + fd * 32 + l31;
                    *(u16*)(Xa + i * 512 + (((dl >> 3) ^ (i & 7)) << 4) + (dl & 7) * 2) = f2bf(acc1[fi][fd][r]);
                }
            }
        __syncthreads();
    }

    // ---- Phase 3+4: GEMM2 (Xagg @ W^T) + LN, TWO row-half passes ----
    float bias_v[2][2], lnw_v[2][2], lnb_v[2][2];
    #pragma unroll
    for (int ch = 0; ch < 2; ++ch)
        #pragma unroll
        for (int fh = 0; fh < 2; ++fh) {
            int h = ch * 256 + wn * 64 + fh * 32 + l31;
            bias_v[ch][fh] = bias[h];
            lnw_v[ch][fh] = lnw[h];
            lnb_v[ch][fh] = lnb[h];
        }
    float* Og = out + (size_t)batch * NN * HH;

#define STAGEW(CH, KS, BUF)                                                               \
    {                                                                                     \
        u16* dst_ = (u16*)(smem + (BUF) * 16384);                                         \
        _Pragma("unroll")                                                                 \
        for (int it_ = 0; it_ < 2; ++it_) {                                               \
            int q_ = it_ * 512 + t;                                                       \
            int h_ = q_ >> 2, cc_ = q_ & 3;                                               \
            gload16(Wb + (size_t)((CH) * 256 + h_) * DD + (KS) * 32 +                     \
                        ((cc_ ^ ((h_ >> 1) & 3)) * 8),                                    \
                    dst_ + q_ * 8);                                                       \
        }                                                                                 \
    }

#define GEMM2_PASS(RH, CH)                                                                \
    {                                                                                     \
        __syncthreads();   /* prior pass LDS reads (W slab / musig) complete */           \
        STAGEW(CH, 0, 0);                                                                 \
        __syncthreads();                                                                  \
        for (int ks = 0; ks < 16; ++ks) {                                                 \
            const int buf = ks & 1;                                                       \
            if (ks < 15) STAGEW(CH, ks + 1, buf ^ 1);                                     \
            const u16* wl = (const u16*)(smem + buf * 16384);                             \
            _Pragma("unroll")                                                             \
            for (int s2 = 0; s2 < 2; ++s2) {                                              \
                const int kc = s2 * 2 + lh;                                               \
                const int ccg = ks * 4 + kc;                                              \
                const int xdh = ccg >> 5, cloc = ccg & 31;                                \
                const char* Xa = smem + 32768 + xdh * 65536;                              \
                const int i_ = (RH) * 64 + wm * 32 + l31;                                 \
                bf16x8 af = *(const bf16x8*)(Xa + i_ * 512 + ((cloc ^ (i_ & 7)) << 4));   \
                bf16x8 bw[2];                                                             \
                _Pragma("unroll")                                                         \
                for (int fh = 0; fh < 2; ++fh) {                                          \
                    int hl = wn * 64 + fh * 32 + l31;                                     \
                    bw[fh] = *(const bf16x8*)(wl + hl * 32 + ((kc ^ ((hl >> 1) & 3)) * 8)); \
                }                                                                         \
                _Pragma("unroll")                                                         \
                for (int fh = 0; fh < 2; ++fh)                                            \
                    acc2[CH][fh] = __builtin_amdgcn_mfma_f32_32x32x16_bf16(               \
                        af, bw[fh], acc2[CH][fh], 0, 0, 0);                               \
            }                                                                             \
            __syncthreads();                                                              \
        }                                                                                 \
    }

#define ROWHALF(RH)                                                                       \
    {                                                                                     \
        f32x16 acc2[2][2];                                                                \
        _Pragma("unroll")                                                                 \
        for (int ch = 0; ch < 2; ++ch)                                                    \
            _Pragma("unroll")                                                             \
            for (int fh = 0; fh < 2; ++fh)                                                \
                _Pragma("unroll")                                                         \
                for (int r = 0; r < 16; ++r)                                              \
                    acc2[ch][fh][r] = 0.f;                                                \
        GEMM2_PASS(RH, 0);                                                                \
        GEMM2_PASS(RH, 1);                                                                \
        /* bias + per-row stats over this wave's 128 h (2ch x 2fh x l31) */               \
        float rs[16], rss[16];                                                            \
        _Pragma("unroll")                                                                 \
        for (int r = 0; r < 16; ++r) {                                                    \
            float s = 0.f, ss = 0.f;                                                      \
            _Pragma("unroll")                                                             \
            for (int ch = 0; ch < 2; ++ch)                                                \
                _Pragma("unroll")                                                         \
                for (int fh = 0; fh < 2; ++fh) {                                          \
                    float a = acc2[ch][fh][r] + bias_v[ch][fh];                           \
                    acc2[ch][fh][r] = a;                                                  \
                    s += a; ss += a * a;                                                  \
                }                                                                         \
            rs[r] = s; rss[r] = ss;                                                       \
        }                                                                                 \
        _Pragma("unroll")                                                                 \
        for (int msk = 1; msk <= 16; msk <<= 1)                                           \
            _Pragma("unroll")                                                             \
            for (int r = 0; r < 16; ++r) {                                                \
                rs[r] += __shfl_xor(rs[r], msk);                                          \
                rss[r] += __shfl_xor(rss[r], msk);                                        \
            }                                                                             \
        if (l31 == 0) {                                                                   \
            _Pragma("unroll")                                                             \
            for (int r = 0; r < 16; ++r) {                                                \
                int rl = wm * 32 + (r & 3) + 8 * (r >> 2) + 4 * lh;                       \
                float2 v; v.x = rs[r]; v.y = rss[r];                                      \
                *(float2*)(Pss + (wn * 64 + rl) * 2) = v;                                 \
            }                                                                             \
        }                                                                                 \
        __syncthreads();                                                                  \
        if (t < 64) {                                                                     \
            float s = 0.f, ss = 0.f;                                                      \
            _Pragma("unroll")                                                             \
            for (int q = 0; q < 4; ++q) {                                                 \
                float2 v = *(const float2*)(Pss + (q * 64 + t) * 2);                      \
                s += v.x; ss += v.y;                                                      \
            }                                                                             \
            float mean = s * (1.0f / 512.0f);                                             \
            float var = ss * (1.0f / 512.0f) - mean * mean;                               \
            float2 mz; mz.x = mean; mz.y = rsqrtf(var + 1e-5f);                           \
            *(float2*)(musig + t * 2) = mz;                                               \
        }                                                                                 \
        __syncthreads();                                                                  \
        _Pragma("unroll")                                                                 \
        for (int r = 0; r < 16; ++r) {                                                    \
            int rl = wm * 32 + (r & 3) + 8 * (r >> 2) + 4 * lh;                           \
            float2 mz = *(const float2*)(musig + rl * 2);                                 \
            _Pragma("unroll")                                                             \
            for (int ch = 0; ch < 2; ++ch)                                                \
                _Pragma("unroll")                                                         \
                for (int fh = 0; fh < 2; ++fh) {                                          \
                    float xn = (acc2[ch][fh][r] - mz.x) * mz.y * lnw_v[ch][fh] + lnb_v[ch][fh]; \
                    Og[(size_t)((RH) * 64 + rl) * HH + ch * 256 + wn * 64 + fh * 32 + l31] =    \
                        1.0f / (1.0f + __expf(-xn));                                      \
                }                                                                         \
        }                                                                                 \
    }

    ROWHALF(0);
    ROWHALF(1);
#undef STAGEW
#undef GEMM2_PASS
#undef ROWHALF
}

extern "C" void kernel_launch(void* const* d_in, const int* in_sizes, int n_in,
                              void* d_out, int out_size, void* d_ws, size_t ws_size,
                              hipStream_t stream) {
    const float* X = (const float*)d_in[0];
    const float* A = (const float*)d_in[1];
    const float* W = (const float*)d_in[2];
    const float* bias = (const float*)d_in[3];
    const float* lnw = (const float*)d_in[4];
    const float* lnb = (const float*)d_in[5];
    float* out = (float*)d_out;

    u16* Wb = (u16*)d_ws;   // H*D bf16 = 512 KB

    hipLaunchKernelGGL(wconv_kernel, dim3(256), dim3(256), 0, stream, W, Wb);
    hipLaunchKernelGGL(fused_kernel, dim3(256), dim3(512), 0, stream, X, A, Wb, bias, lnw, lnb, out);
}

// Round 12
// 78.519 us; speedup vs baseline: 1.1168x; 1.1168x over previous
//
#include <hip/hip_runtime.h>
#include <cstdint>

#define BB 256
#define NN 128
#define DD 512
#define HH 512

typedef __attribute__((ext_vector_type(8))) short bf16x8;
typedef __attribute__((ext_vector_type(16))) float f32x16;
typedef unsigned short u16;

static __device__ __forceinline__ u16 f2bf(float f) {
    union { float f; uint32_t u; } v; v.f = f;
    uint32_t u = v.u;
    return (u16)((u + 0x7FFFu + ((u >> 16) & 1u)) >> 16);
}

static __device__ __forceinline__ void gload16(const u16* g, u16* l) {
    __builtin_amdgcn_global_load_lds((const __attribute__((address_space(1))) void*)g,
                                     (__attribute__((address_space(3))) void*)l, 16, 0, 0);
}

// ---------------- W fp32 -> bf16 (once) ----------------
__global__ __launch_bounds__(256) void wconv_kernel(const float* __restrict__ W, u16* __restrict__ Wb) {
    int idx = (blockIdx.x * 256 + threadIdx.x) * 4;
    float4 v = *(const float4*)(W + idx);
    ushort4 o;
    o.x = f2bf(v.x); o.y = f2bf(v.y); o.z = f2bf(v.z); o.w = f2bf(v.w);
    *(ushort4*)(Wb + idx) = o;
}

// ---------------- Xagg = (I + A_norm) @ X -> HBM bf16 ----------------
// 1 block/batch (256 blocks = 1/CU), 512 thr = 8 waves (wm = w>>2, wn = w&3).
// LDS: Ms[128][128] 32K + Xt[512][128] 128K = 160K. Xt read-only after staging
// -> dh loop has NO barriers.
__global__ __launch_bounds__(512) void agg_kernel(const float* __restrict__ X, const float* __restrict__ A,
                                                  u16* __restrict__ Xagg) {
    __shared__ __align__(16) char smem[163840];
    u16* Ms = (u16*)smem;                 // [128 i][128 m], chunk c' = c ^ (i&15)
    u16* Xt = (u16*)(smem + 32768);       // [512 d][128 m], chunk c' = c ^ ((d>>2)&7)

    const int t = threadIdx.x;
    const int lane = t & 63, w = t >> 6, l31 = lane & 31, lh = lane >> 5;
    const int batch = blockIdx.x;
    const int wm = w >> 2, wn = w & 3;

    // ---- Phase 1a: M = A_norm + I ----
    {
        const int row = t >> 2, seg = t & 3;
        const float* Ag = A + (size_t)batch * NN * NN + row * NN + seg * 32;
        float4 a[8];
        #pragma unroll
        for (int j = 0; j < 8; ++j) a[j] = *(const float4*)(Ag + j * 4);
        float s = 0.f;
        #pragma unroll
        for (int j = 0; j < 8; ++j) s += a[j].x + a[j].y + a[j].z + a[j].w;
        s += __shfl_xor(s, 1);
        s += __shfl_xor(s, 2);
        const float inv = 1.0f / (s + 1e-6f);
        #pragma unroll
        for (int c2 = 0; c2 < 4; ++c2) {
            u16 tmp[8];
            const float* pe = (const float*)&a[c2 * 2];
            #pragma unroll
            for (int e = 0; e < 8; ++e) {
                int m = seg * 32 + c2 * 8 + e;
                tmp[e] = f2bf(pe[e] * inv + (m == row ? 1.0f : 0.0f));
            }
            int c = seg * 4 + c2;
            *(uint4*)(Ms + row * 128 + ((c ^ (row & 15)) << 3)) = *(const uint4*)tmp;
        }
    }

    // ---- Phase 1b: Xt[d][m] = X[m][d] bf16 swizzled ----
    {
        const float* Xg = X + (size_t)batch * NN * DD;
        #pragma unroll
        for (int it = 0; it < 32; ++it) {
            int q = it * 512 + t;
            int m = q >> 7, c4 = q & 127;
            float4 v = *(const float4*)(Xg + (size_t)m * DD + c4 * 4);
            float fv[4] = {v.x, v.y, v.z, v.w};
            #pragma unroll
            for (int j = 0; j < 4; ++j) {
                int d = c4 * 4 + j;
                Xt[d * 128 + (((m >> 3) ^ ((d >> 2) & 7)) << 3) + (m & 7)] = f2bf(fv[j]);
            }
        }
    }
    __syncthreads();

    // ---- Phase 2: GEMM1 per d-half, write Xagg bf16 straight to HBM ----
    u16* Og = Xagg + (size_t)batch * NN * DD;
    #pragma unroll
    for (int dh = 0; dh < 2; ++dh) {
        f32x16 acc1[2][2];
        #pragma unroll
        for (int fi = 0; fi < 2; ++fi)
            #pragma unroll
            for (int fd = 0; fd < 2; ++fd)
                #pragma unroll
                for (int r = 0; r < 16; ++r)
                    acc1[fi][fd][r] = 0.f;

        #pragma unroll
        for (int ksl = 0; ksl < 8; ++ksl) {
            const int kc = ksl * 2 + lh;
            bf16x8 af[2], bx[2];
            #pragma unroll
            for (int fi = 0; fi < 2; ++fi) {
                int i = wm * 64 + fi * 32 + l31;
                af[fi] = *(const bf16x8*)(Ms + i * 128 + ((kc ^ (i & 15)) << 3));
            }
            #pragma unroll
            for (int fd = 0; fd < 2; ++fd) {
                int d = dh * 256 + wn * 64 + fd * 32 + l31;
                bx[fd] = *(const bf16x8*)(Xt + d * 128 + ((kc ^ ((d >> 2) & 7)) << 3));
            }
            #pragma unroll
            for (int fi = 0; fi < 2; ++fi)
                #pragma unroll
                for (int fd = 0; fd < 2; ++fd)
                    acc1[fi][fd] = __builtin_amdgcn_mfma_f32_32x32x16_bf16(af[fi], bx[fd], acc1[fi][fd], 0, 0, 0);
        }

        #pragma unroll
        for (int fi = 0; fi < 2; ++fi)
            #pragma unroll
            for (int r = 0; r < 16; ++r) {
                int i = wm * 64 + fi * 32 + (r & 3) + 8 * (r >> 2) + 4 * lh;
                #pragma unroll
                for (int fd = 0; fd < 2; ++fd) {
                    int d = dh * 256 + wn * 64 + fd * 32 + l31;
                    Og[(size_t)i * DD + d] = f2bf(acc1[fi][fd][r]);
                }
            }
    }
}

// ---------------- out = sigmoid(LN( Xagg @ W^T + bias )) ----------------
// grid 512 (M-tile 64), 512 thr = 8 waves (wm = w>>2 -> 32-row strip, wn = w&3 -> 128-h strip).
// LDS 72K (W slabs 2x32K + A slabs 2x4K) -> 2 blocks/CU; acc[4] = 64 VGPR, fits the
// 128-VGPR cap implied by __launch_bounds__(512,2) -> no spill (R9-R11 lesson).
__global__ __launch_bounds__(512, 2) void gemm_ln_kernel(const u16* __restrict__ Xagg, const u16* __restrict__ Wb,
                                                         const float* __restrict__ bias, const float* __restrict__ lnw,
                                                         const float* __restrict__ lnb, float* __restrict__ out) {
    __shared__ __align__(16) char smem[73728];   // W slabs 2x32K @0; A slabs 2x4K @65536
    float* Pss = (float*)smem;                   // overlay after K-loop: [4 wn][64 row][2]
    float* musig = (float*)(smem + 2048);        // [64 row][2]

    const int t = threadIdx.x;
    const int lane = t & 63, w = t >> 6, l31 = lane & 31, lh = lane >> 5;
    const int wm = w >> 2, wn = w & 3;
    const size_t rb = (size_t)blockIdx.x * 64;
    const u16* Xab = Xagg + rb * DD;

    float bias_v[4], lnw_v[4], lnb_v[4];
    #pragma unroll
    for (int fh = 0; fh < 4; ++fh) {
        int h = wn * 128 + fh * 32 + l31;
        bias_v[fh] = bias[h];
        lnw_v[fh] = lnw[h];
        lnb_v[fh] = lnb[h];
    }

#define STAGE(KS, BUF)                                                               \
    {                                                                                \
        const int k0_ = (KS) * 32;                                                   \
        u16* wl_ = (u16*)(smem + (BUF) * 32768);                                     \
        u16* xal_ = (u16*)(smem + 65536 + (BUF) * 4096);                             \
        _Pragma("unroll")                                                            \
        for (int it_ = 0; it_ < 4; ++it_) {                                          \
            int q_ = it_ * 512 + t;                                                  \
            int h_ = q_ >> 2, cc_ = q_ & 3;                                          \
            gload16(Wb + (size_t)h_ * DD + k0_ + ((cc_ ^ ((h_ >> 1) & 3)) * 8),      \
                    wl_ + q_ * 8);                                                   \
        }                                                                            \
        if (t < 256) {                                                               \
            int m_ = t >> 2, cc_ = t & 3;                                            \
            gload16(Xab + (size_t)m_ * DD + k0_ + ((cc_ ^ ((m_ >> 1) & 3)) * 8),     \
                    xal_ + t * 8);                                                   \
        }                                                                            \
    }

    f32x16 acc[4];
    #pragma unroll
    for (int fh = 0; fh < 4; ++fh)
        #pragma unroll
        for (int r = 0; r < 16; ++r)
            acc[fh][r] = 0.f;

    STAGE(0, 0);
    for (int ks = 0; ks < 16; ++ks) {
        const int buf = ks & 1;
        if (ks < 15) {
            STAGE(ks + 1, buf ^ 1);
            if (t < 256) asm volatile("s_waitcnt vmcnt(5)" ::: "memory");
            else         asm volatile("s_waitcnt vmcnt(4)" ::: "memory");
        } else {
            asm volatile("s_waitcnt vmcnt(0)" ::: "memory");
        }
        __builtin_amdgcn_s_barrier();
        asm volatile("" ::: "memory");

        const u16* wl = (const u16*)(smem + buf * 32768);
        const u16* xal = (const u16*)(smem + 65536 + buf * 4096);
        #pragma unroll
        for (int s2 = 0; s2 < 2; ++s2) {
            const int kc = s2 * 2 + lh;
            const int m = wm * 32 + l31;
            bf16x8 af = *(const bf16x8*)(xal + (m * 4 + (kc ^ ((m >> 1) & 3))) * 8);
            bf16x8 bw[4];
            #pragma unroll
            for (int fh = 0; fh < 4; ++fh) {
                int h = wn * 128 + fh * 32 + l31;
                bw[fh] = *(const bf16x8*)(wl + (h * 4 + (kc ^ ((h >> 1) & 3))) * 8);
            }
            #pragma unroll
            for (int fh = 0; fh < 4; ++fh)
                acc[fh] = __builtin_amdgcn_mfma_f32_32x32x16_bf16(af, bw[fh], acc[fh], 0, 0, 0);
        }
        asm volatile("" ::: "memory");
        __builtin_amdgcn_s_barrier();
    }
#undef STAGE
    __syncthreads();   // slabs dead; overlay stats

    // bias + per-row stats over this wave's 128 h
    float rs[16], rss[16];
    #pragma unroll
    for (int r = 0; r < 16; ++r) {
        float s = 0.f, ss = 0.f;
        #pragma unroll
        for (int fh = 0; fh < 4; ++fh) {
            float a = acc[fh][r] + bias_v[fh];
            acc[fh][r] = a;
            s += a; ss += a * a;
        }
        rs[r] = s; rss[r] = ss;
    }
    #pragma unroll
    for (int msk = 1; msk <= 16; msk <<= 1)
        #pragma unroll
        for (int r = 0; r < 16; ++r) {
            rs[r] += __shfl_xor(rs[r], msk);
            rss[r] += __shfl_xor(rss[r], msk);
        }
    if (l31 == 0) {
        #pragma unroll
        for (int r = 0; r < 16; ++r) {
            int rl = wm * 32 + (r & 3) + 8 * (r >> 2) + 4 * lh;
            float2 v; v.x = rs[r]; v.y = rss[r];
            *(float2*)(Pss + (wn * 64 + rl) * 2) = v;
        }
    }
    __syncthreads();
    if (t < 64) {
        float s = 0.f, ss = 0.f;
        #pragma unroll
        for (int q = 0; q < 4; ++q) {
            float2 v = *(const float2*)(Pss + (q * 64 + t) * 2);
            s += v.x; ss += v.y;
        }
        float mean = s * (1.0f / 512.0f);
        float var = ss * (1.0f / 512.0f) - mean * mean;
        float2 mz; mz.x = mean; mz.y = rsqrtf(var + 1e-5f);
        *(float2*)(musig + t * 2) = mz;
    }
    __syncthreads();

    #pragma unroll
    for (int r = 0; r < 16; ++r) {
        int rl = wm * 32 + (r & 3) + 8 * (r >> 2) + 4 * lh;
        float2 mz = *(const float2*)(musig + rl * 2);
        #pragma unroll
        for (int fh = 0; fh < 4; ++fh) {
            float xn = (acc[fh][r] - mz.x) * mz.y * lnw_v[fh] + lnb_v[fh];
            out[(rb + rl) * HH + wn * 128 + fh * 32 + l31] = 1.0f / (1.0f + __expf(-xn));
        }
    }
}

extern "C" void kernel_launch(void* const* d_in, const int* in_sizes, int n_in,
                              void* d_out, int out_size, void* d_ws, size_t ws_size,
                              hipStream_t stream) {
    const float* X = (const float*)d_in[0];
    const float* A = (const float*)d_in[1];
    const float* W = (const float*)d_in[2];
    const float* bias = (const float*)d_in[3];
    const float* lnw = (const float*)d_in[4];
    const float* lnb = (const float*)d_in[5];
    float* out = (float*)d_out;

    u16* Xagg = (u16*)d_ws;                                  // B*N*D bf16 = 32 MB
    u16* Wb = (u16*)d_ws + (size_t)BB * NN * DD;             // H*D bf16 = 512 KB

    hipLaunchKernelGGL(wconv_kernel, dim3(256), dim3(256), 0, stream, W, Wb);
    hipLaunchKernelGGL(agg_kernel, dim3(256), dim3(512), 0, stream, X, A, Xagg);
    hipLaunchKernelGGL(gemm_ln_kernel, dim3(512), dim3(512), 0, stream, Xagg, Wb, bias, lnw, lnb, out);
}